// Round 9
// baseline (270.790 us; speedup 1.0000x reference)
//
#include <hip/hip_runtime.h>
#include <hip/hip_bf16.h>

typedef unsigned short ushort_t;
typedef __attribute__((ext_vector_type(4))) float v4f;
typedef __attribute__((ext_vector_type(8))) short v8s;

#define FDIM 128
#define KCLUST 16
#define QSTRIDE 24    // q row stride in shorts (48B)
#define MSTRIDE 20    // mask row stride in shorts (40B) -> conflict-free frag reads
#define SS 10         // compile-time S fast path

__device__ __forceinline__ ushort_t f2bf(float x) {
    unsigned int u = __float_as_uint(x);
    unsigned int r = (u + 0x7fffu + ((u >> 16) & 1u)) >> 16;
    return (ushort_t)r;
}
__device__ __forceinline__ float bf2f(ushort_t h) {
    return __uint_as_float((unsigned int)h << 16);
}
__device__ __forceinline__ float wave_reduce_sum(float v) {
    #pragma unroll
    for (int off = 32; off > 0; off >>= 1) v += __shfl_xor(v, off, 64);
    return v;
}

union V8U { v8s v; ushort_t u[8]; };

// ---------------------------------------------------------------------------
// Kernel 1: cast weight (E x 256 f32) -> bf16, padded to Np rows (zeros).
// ---------------------------------------------------------------------------
__global__ void pack_weight(const float* __restrict__ W, ushort_t* __restrict__ Wb,
                            long total, long valid) {
    long i = ((long)blockIdx.x * blockDim.x + threadIdx.x) * 4;
    if (i >= total) return;
    float4 v;
    if (i < valid) v = *(const float4*)(W + i);
    else           v = make_float4(0.f, 0.f, 0.f, 0.f);
    ushort_t* dst = Wb + i;
    dst[0] = f2bf(v.x); dst[1] = f2bf(v.y); dst[2] = f2bf(v.z); dst[3] = f2bf(v.w);
}

// ---------------------------------------------------------------------------
// Kernel 2 (v10): ONE WAVE = ONE ROW, zero loop barriers.
//   v4/v6/v8/v9 (4 different schedules) all plateau at 60-72us with no pipe
//   >32% busy: block-granular latency exposure from barrier-coupled waves at
//   ~1.5 blocks/CU. v10 makes every wave fully independent:
//   - ln/n2: 6-step butterfly allreduce -> att/n2 in ALL lanes' registers
//     (no LDS scratch, no extraction, no runtime-indexed arrays).
//   - cross[10,16] = N @ C^T: 4 MFMA, A-frags from a PER-WAVE XOR-swizzled
//     LDS buffer (wave-local lgkmcnt waits; v9's verified swizzle).
//   - q split-bf16 + per-wave LDS transpose (v9's verified pattern).
//   - m[s][f] over all 8 f-tiles: 3 MFMA/tile, mask bf16 hi/lo staged ONCE
//     per block in shared LDS [f][k] stride-20 (the only barrier, at entry).
//   - final sum over s: 2 shuffles; comb row (bf16) -> workspace.
//   Phase B is a separate barrier-free GEMM kernel (comb round trip = 10MB).
// ---------------------------------------------------------------------------
__global__ __launch_bounds__(256, 2) void agg_s10(
    const int* __restrict__ nodes, const int* __restrict__ neigh_idx,
    const float* __restrict__ self_table, const float* __restrict__ neigh_table,
    const float* __restrict__ center, const float* __restrict__ cluster_mask,
    const float* __restrict__ alpha, ushort_t* __restrict__ combW, int B) {

    __shared__ __align__(16) ushort_t mh[128 * MSTRIDE];   // mask hi [f][k]
    __shared__ __align__(16) ushort_t ml_[128 * MSTRIDE];  // mask lo [f][k]
    __shared__ __align__(16) float    zslot[4];            // 16B zeros
    __shared__ __align__(16) ushort_t nb[4][16 * 128];     // per-wave swizzled N (bf16)
    __shared__ __align__(16) ushort_t qh_[4][16 * QSTRIDE];
    __shared__ __align__(16) ushort_t ql_[4][16 * QSTRIDE];

    const int t = threadIdx.x, lane = t & 63, wave = t >> 6;
    const int l16 = lane & 15, quad = lane >> 4;
    const int b = blockIdx.x * 4 + wave;
    const bool valid = b < B;
    const int bc = valid ? b : B - 1;

    // ---- early independent loads (latency overlaps staging below) ----
    int idxv[SS];
    #pragma unroll
    for (int j = 0; j < SS; j++) idxv[j] = neigh_idx[(size_t)bc * SS + j];

    const float as0 = alpha[lane], as1 = alpha[64 + lane];
    const float an0 = alpha[128 + lane], an1 = alpha[192 + lane];
    const size_t node = (size_t)nodes[bc];
    const float s0 = self_table[node * FDIM + lane];
    const float s1 = self_table[node * FDIM + 64 + lane];

    // center B-frags + c2 (every wave; c2v = c2[l16] after quad-reduce)
    v8s cbf[4]; float c2v = 0.f;
    {
        const float* crow = center + l16 * FDIM;
        #pragma unroll
        for (int kk = 0; kk < 4; kk++) {
            const float* p = crow + kk * 32 + quad * 8;
            float4 x = *(const float4*)p;
            float4 y = *(const float4*)(p + 4);
            V8U pk;
            pk.u[0] = f2bf(x.x); pk.u[1] = f2bf(x.y); pk.u[2] = f2bf(x.z); pk.u[3] = f2bf(x.w);
            pk.u[4] = f2bf(y.x); pk.u[5] = f2bf(y.y); pk.u[6] = f2bf(y.z); pk.u[7] = f2bf(y.w);
            cbf[kk] = pk.v;
            c2v += x.x*x.x + x.y*x.y + x.z*x.z + x.w*x.w
                 + y.x*y.x + y.y*y.y + y.z*y.z + y.w*y.w;
        }
        c2v += __shfl_xor(c2v, 16, 64);
        c2v += __shfl_xor(c2v, 32, 64);
    }

    // neighbor gathers (f32, 20 loads, bulk-issued)
    float n0[SS], n1[SS];
    #pragma unroll
    for (int j = 0; j < SS; j++) {
        const float* p = neigh_table + (size_t)idxv[j] * FDIM;
        n0[j] = p[lane]; n1[j] = p[64 + lane];
    }

    // ---- block-shared mask staging (the only barrier) ----
    for (int i = t; i < KCLUST * FDIM; i += 256) {
        const int k = i >> 7, f = i & 127;
        const float mv = cluster_mask[k * FDIM + f];
        const ushort_t h = f2bf(mv);
        mh[f * MSTRIDE + k] = h;
        ml_[f * MSTRIDE + k] = f2bf(mv - bf2f(h));
    }
    for (int i = t; i < 512; i += 256) {   // zero the 4 pad slots per row
        const int f = i >> 2, j = i & 3;
        mh[f * MSTRIDE + 16 + j] = 0; ml_[f * MSTRIDE + 16 + j] = 0;
    }
    if (t < 4) zslot[t] = 0.f;
    #pragma unroll
    for (int rr = 0; rr < 6; rr++)        // zero nb rows 10..15 (cross reads them)
        ((unsigned*)(nb[wave] + (10 + rr) * 128))[lane] = 0u;

    asm volatile("s_waitcnt lgkmcnt(0)" ::: "memory");
    __builtin_amdgcn_s_barrier();
    asm volatile("" ::: "memory");

    // ---- ls + per-s butterflies (allreduce: results in every lane) ----
    float ls = s0 * as0 + s1 * as1;
    #pragma unroll
    for (int off = 32; off > 0; off >>= 1) ls += __shfl_xor(ls, off, 64);

    float att[SS], p2a[SS]; float attsum = 0.f;
    #pragma unroll
    for (int j = 0; j < SS; j++) {
        float pn = n0[j] * an0 + n1[j] * an1;
        float p2 = n0[j] * n0[j] + n1[j] * n1[j];
        #pragma unroll
        for (int off = 32; off > 0; off >>= 1) {
            pn += __shfl_xor(pn, off, 64);
            p2 += __shfl_xor(p2, off, 64);
        }
        att[j] = __expf(fmaxf(ls + pn, 0.f));
        attsum += att[j];
        p2a[j] = p2;
        // stage bf16 N, XOR-swizzled 16B chunks (chunk c of row j at c^j)
        {
            char* base = (char*)nb[wave] + j * 256;
            const int c0 = lane >> 3, c1 = 8 + (lane >> 3);
            *(ushort_t*)(base + (((c0 ^ j) << 4)) + (lane & 7) * 2) = f2bf(n0[j]);
            *(ushort_t*)(base + (((c1 ^ j) << 4)) + (lane & 7) * 2) = f2bf(n1[j]);
        }
    }

    // ---- per-lane selects (compile-time indices only; rule #20) ----
    float n2q[4], attq[4]; int idxq[4];
    #pragma unroll
    for (int r = 0; r < 4; r++) {
        n2q[r]  = quad == 0 ? p2a[r] : quad == 1 ? p2a[4 + r]
                : (quad == 2 && r < 2) ? p2a[8 + r] : 0.f;
        attq[r] = quad == 0 ? att[r] : quad == 1 ? att[4 + r]
                : (quad == 2 && r < 2) ? att[8 + r] : 0.f;
        idxq[r] = quad == 0 ? idxv[r] : quad == 1 ? idxv[4 + r]
                : (quad == 2 && r < 2) ? idxv[8 + r] : idxv[0];
    }

    // ---- issue f32 n-reloads for the final product (hide under cross) ----
    float nfin[4][8];
    #pragma unroll
    for (int r = 0; r < 4; r++) {
        const float* p = neigh_table + (size_t)idxq[r] * FDIM + l16;
        #pragma unroll
        for (int tile = 0; tile < 8; tile++) nfin[r][tile] = p[tile * 16];
    }

    // ---- cross[10,16] = N @ C^T (wave-local; 4 MFMA) ----
    asm volatile("s_waitcnt lgkmcnt(0)" ::: "memory");
    __builtin_amdgcn_sched_barrier(0);
    v4f xacc = {0.f, 0.f, 0.f, 0.f};
    #pragma unroll
    for (int kk = 0; kk < 4; kk++) {
        v8s af = *(const v8s*)((char*)nb[wave] + l16 * 256 + (((kk * 4 + quad) ^ l16) << 4));
        xacc = __builtin_amdgcn_mfma_f32_16x16x32_bf16(af, cbf[kk], xacc, 0, 0, 0);
    }

    // ---- q (split bf16) + per-wave transpose ----
    #pragma unroll
    for (int r = 0; r < 4; r++) {
        const float d  = n2q[r] - 2.f * xacc[r] + c2v;
        const float qv = 1.f / (d + 1.f);
        const ushort_t h = f2bf(qv);
        qh_[wave][(quad * 4 + r) * QSTRIDE + l16] = h;
        ql_[wave][(quad * 4 + r) * QSTRIDE + l16] = f2bf(qv - bf2f(h));
    }
    asm volatile("s_waitcnt lgkmcnt(0)" ::: "memory");
    __builtin_amdgcn_sched_barrier(0);
    v8s aqh = *(const v8s*)((char*)qh_[wave] + l16 * 48 + (quad & 1) * 16);
    v8s aql = *(const v8s*)((char*)ql_[wave] + l16 * 48 + (quad & 1) * 16);

    // ---- m over all 8 f-tiles + weighted combine ----
    float acc[8];
    #pragma unroll
    for (int tile = 0; tile < 8; tile++) acc[tile] = 0.f;
    #pragma unroll
    for (int tile = 0; tile < 8; tile++) {
        const int f = tile * 16 + l16;
        v8s bh = (quad < 2) ? *(const v8s*)((char*)mh  + f * 40 + quad * 16)
                            : *(const v8s*)zslot;
        v8s bl = (quad < 2) ? *(const v8s*)((char*)ml_ + f * 40 + quad * 16)
                            : *(const v8s*)zslot;
        v4f mac = {0.f, 0.f, 0.f, 0.f};
        mac = __builtin_amdgcn_mfma_f32_16x16x32_bf16(aqh, bh, mac, 0, 0, 0);
        mac = __builtin_amdgcn_mfma_f32_16x16x32_bf16(aql, bh, mac, 0, 0, 0);
        mac = __builtin_amdgcn_mfma_f32_16x16x32_bf16(aqh, bl, mac, 0, 0, 0);
        #pragma unroll
        for (int r = 0; r < 4; r++)
            acc[tile] = fmaf(attq[r] * mac[r], nfin[r][tile], acc[tile]);
    }

    // fold quads (s = quad*4+r covered 16 s; att=0 masks s>=10)
    #pragma unroll
    for (int tile = 0; tile < 8; tile++) {
        acc[tile] += __shfl_xor(acc[tile], 16, 64);
        acc[tile] += __shfl_xor(acc[tile], 32, 64);
    }

    if (valid) {
        const float inv = 1.f / attsum;
        ushort_t* cw = combW + (size_t)b * 256;
        cw[lane]      = f2bf(s0);
        cw[64 + lane] = f2bf(s1);
        if (quad == 0) {
            #pragma unroll
            for (int tile = 0; tile < 8; tile++)
                cw[128 + tile * 16 + l16] = f2bf(acc[tile] * inv);
        }
    }
}

// ---------------------------------------------------------------------------
// Kernel 3 (v10): out[B][E] = relu(comb @ Wb^T). Barrier-free, no LDS.
// ---------------------------------------------------------------------------
__global__ __launch_bounds__(256, 2) void gemm_out(
    const ushort_t* __restrict__ combW, const ushort_t* __restrict__ Wb,
    float* __restrict__ out, int B, int E) {

    const int t = threadIdx.x, lane = t & 63, wave = t >> 6;
    const int l16 = lane & 15, quad = lane >> 4;
    const int b0 = blockIdx.x * 16;
    const int Ntiles = (E + 15) >> 4;

    int arow = b0 + l16; if (arow >= B) arow = B - 1;   // clamp: avoid poison
    v8s afr[8];
    #pragma unroll
    for (int kk = 0; kk < 8; kk++)
        afr[kk] = *(const v8s*)(combW + (size_t)arow * 256 + kk * 32 + quad * 8);

    for (int nt = wave; nt < Ntiles; nt += 4) {
        const ushort_t* wrow = Wb + (size_t)(nt * 16 + l16) * 256 + quad * 8;
        v4f acc = {0.f, 0.f, 0.f, 0.f};
        #pragma unroll
        for (int kk = 0; kk < 8; kk++) {
            v8s bfr = *(const v8s*)(wrow + kk * 32);
            acc = __builtin_amdgcn_mfma_f32_16x16x32_bf16(afr[kk], bfr, acc, 0, 0, 0);
        }
        const int gcol = nt * 16 + l16;
        if (gcol < E) {
            #pragma unroll
            for (int rr = 0; rr < 4; rr++) {
                const int grow = b0 + quad * 4 + rr;
                if (grow < B)
                    out[(size_t)grow * E + gcol] = fmaxf(acc[rr], 0.f);
            }
        }
    }
}

// ---------------------------------------------------------------------------
// Generic fallback (any S), exact f32. Kept for non-benched shapes.
// ---------------------------------------------------------------------------
__global__ void fused_generic(
    const int* __restrict__ nodes, const int* __restrict__ neigh_idx,
    const float* __restrict__ self_table, const float* __restrict__ neigh_table,
    const float* __restrict__ center, const float* __restrict__ cluster_mask,
    const float* __restrict__ alpha, const float* __restrict__ weight,
    float* __restrict__ out, int B, int S, int E) {

    __shared__ float combsh[256];
    const int b = blockIdx.x;
    const int lane = threadIdx.x;  // 64 threads

    float s0 = self_table[(size_t)nodes[b] * FDIM + lane];
    float s1 = self_table[(size_t)nodes[b] * FDIM + 64 + lane];
    const float ls = wave_reduce_sum(s0 * alpha[lane] + s1 * alpha[64 + lane]);

    float acc0 = 0.f, acc1 = 0.f, attsum = 0.f;
    for (int s = 0; s < S; s++) {
        const size_t idx = (size_t)neigh_idx[(size_t)b * S + s];
        const float n0 = neigh_table[idx * FDIM + lane];
        const float n1 = neigh_table[idx * FDIM + 64 + lane];
        const float ln = wave_reduce_sum(n0 * alpha[128 + lane] + n1 * alpha[192 + lane]);
        const float att = __expf(fmaxf(ls + ln, 0.f));
        float m0 = 0.f, m1 = 0.f;
        for (int k = 0; k < KCLUST; k++) {
            const float c0 = center[k * FDIM + lane];
            const float c1 = center[k * FDIM + 64 + lane];
            const float d = wave_reduce_sum((n0 - c0) * (n0 - c0) + (n1 - c1) * (n1 - c1));
            const float qv = 1.f / (d + 1.f);
            m0 += qv * cluster_mask[k * FDIM + lane];
            m1 += qv * cluster_mask[k * FDIM + 64 + lane];
        }
        acc0 += att * n0 * m0; acc1 += att * n1 * m1; attsum += att;
    }
    const float inv = 1.f / attsum;
    combsh[lane] = s0; combsh[64 + lane] = s1;
    combsh[128 + lane] = acc0 * inv; combsh[192 + lane] = acc1 * inv;
    __syncthreads();
    for (int e = lane; e < E; e += 64) {
        const float* wr = weight + (size_t)e * 256;
        float o = 0.f;
        for (int j = 0; j < 256; j++) o += combsh[j] * wr[j];
        out[(size_t)b * E + e] = fmaxf(o, 0.f);
    }
}

extern "C" void kernel_launch(void* const* d_in, const int* in_sizes, int n_in,
                              void* d_out, int out_size, void* d_ws, size_t ws_size,
                              hipStream_t stream) {
    const int*   nodes        = (const int*)d_in[0];
    const int*   neigh_idx    = (const int*)d_in[1];
    const float* self_table   = (const float*)d_in[2];
    const float* neigh_table  = (const float*)d_in[3];
    const float* center       = (const float*)d_in[4];
    const float* cluster_mask = (const float*)d_in[5];
    const float* weight       = (const float*)d_in[6];
    const float* alpha        = (const float*)d_in[7];
    float* out = (float*)d_out;

    int B = in_sizes[0];
    int S = in_sizes[1] / B;
    int E = in_sizes[6] / (2 * FDIM);

    if (S == SS) {
        int Np = ((E + 15) / 16) * 16;
        ushort_t* Wb   = (ushort_t*)d_ws;               // Np x 256 bf16
        ushort_t* comb = Wb + (size_t)Np * 256;         // B x 256 bf16 (16B-aligned)

        long totalW = (long)Np * 256;
        long validW = (long)E * 256;
        int blksW = (int)((totalW + 1023) / 1024);
        pack_weight<<<blksW, 256, 0, stream>>>(weight, Wb, totalW, validW);

        int nblkA = (B + 3) / 4;
        agg_s10<<<nblkA, 256, 0, stream>>>(
            nodes, neigh_idx, self_table, neigh_table, center, cluster_mask,
            alpha, comb, B);

        int nblkG = (B + 15) / 16;
        gemm_out<<<nblkG, 256, 0, stream>>>(comb, Wb, out, B, E);
    } else {
        fused_generic<<<B, 64, 0, stream>>>(
            nodes, neigh_idx, self_table, neigh_table, center, cluster_mask,
            alpha, weight, out, B, S, E);
    }
}